// Round 3
// baseline (851.073 us; speedup 1.0000x reference)
//
#include <hip/hip_runtime.h>
#include <math.h>

#define BB 16
#define CC 64
#define NN 2048
#define KK 8
#define CAND 16   // phase-1 candidates kept per query (exact top-8 is a subset)
#define TM 128    // m-tile staged in LDS

__device__ __forceinline__ bool betterf(float d1, int i1, float d2, int i2) {
    return (d1 < d2) || (d1 == d2 && i1 < i2);   // smaller distance, tie -> lower idx
}
__device__ __forceinline__ bool betterd(double d1, int i1, double d2, int i2) {
    return (d1 < d2) || (d1 == d2 && i1 < i2);
}

__global__ __launch_bounds__(256) void knn_upsample(const float* __restrict__ x,
                                                    float* __restrict__ out) {
    __shared__ float xs[CC][TM];   // 32 KB tile: [channel][m]
    __shared__ float qs[4][CC];    // 4 query points (one per wave)

    const int tid  = threadIdx.x;
    const int w    = tid >> 6;     // wave id 0..3
    const int lane = tid & 63;
    const int blk  = blockIdx.x;
    const int b    = blk >> 9;            // 512 blocks per batch
    const int n0   = (blk & 511) << 2;    // 4 points per block
    const int n    = n0 + w;              // this wave's query point
    const float* xb = x + b * (CC * NN);

    qs[w][lane] = xb[lane * NN + n];
    __syncthreads();
    float q[CC];
#pragma unroll
    for (int c = 0; c < CC; ++c) q[c] = qs[w][c];

    // ---------------- phase 1: fp32 top-16 ----------------
    float d16[CAND]; int i16[CAND];
#pragma unroll
    for (int j = 0; j < CAND; ++j) { d16[j] = INFINITY; i16[j] = 0x7fffffff; }

    for (int m0 = 0; m0 < NN; m0 += TM) {
        __syncthreads();
        // cooperative float4 tile load: CC*TM/4 = 2048 float4s, 8 per thread
#pragma unroll
        for (int r = 0; r < (CC * TM / 4) / 256; ++r) {
            int v  = r * 256 + tid;
            int c  = v >> 5;          // / (TM/4)
            int mv = v & 31;          // % (TM/4)
            *(float4*)(&xs[c][mv * 4]) = *(const float4*)(xb + c * NN + m0 + mv * 4);
        }
        __syncthreads();

#pragma unroll
        for (int mmi = 0; mmi < TM / 64; ++mmi) {
            int mm = mmi * 64 + lane;
            int m  = m0 + mm;
            float d = 0.f;
#pragma unroll
            for (int c = 0; c < CC; ++c) {
                float t = xs[c][mm] - q[c];
                d = fmaf(t, t, d);
            }
            if (m != n && betterf(d, m, d16[CAND - 1], i16[CAND - 1])) {
                int pos = CAND - 1;
#pragma unroll
                for (int j = CAND - 2; j >= 0; --j)
                    if (betterf(d, m, d16[j], i16[j])) pos = j;
#pragma unroll
                for (int j = CAND - 1; j > 0; --j)
                    if (j > pos) { d16[j] = d16[j - 1]; i16[j] = i16[j - 1]; }
                d16[pos] = d; i16[pos] = m;
            }
        }
    }

    // butterfly merge: all 64 lanes end up holding the wave-global top-16
#pragma unroll
    for (int off = 1; off < 64; off <<= 1) {
        float pd[CAND]; int pi[CAND];
#pragma unroll
        for (int j = 0; j < CAND; ++j) {
            pd[j] = __shfl_xor(d16[j], off, 64);
            pi[j] = __shfl_xor(i16[j], off, 64);
        }
        float cd[CAND]; int ci[CAND];
#pragma unroll
        for (int j = 0; j < CAND; ++j) {
            if (betterf(d16[j], i16[j], pd[CAND - 1 - j], pi[CAND - 1 - j])) {
                cd[j] = d16[j]; ci[j] = i16[j];
            } else {
                cd[j] = pd[CAND - 1 - j]; ci[j] = pi[CAND - 1 - j];
            }
        }
        // bitonic cleanup for 16 (best-first): distances 8,4,2,1
#define CMPEX(a_, b_) { if (betterf(cd[b_], ci[b_], cd[a_], ci[a_])) { \
            float td = cd[a_]; cd[a_] = cd[b_]; cd[b_] = td; \
            int   ti = ci[a_]; ci[a_] = ci[b_]; ci[b_] = ti; } }
        CMPEX(0,8) CMPEX(1,9) CMPEX(2,10) CMPEX(3,11) CMPEX(4,12) CMPEX(5,13) CMPEX(6,14) CMPEX(7,15)
        CMPEX(0,4) CMPEX(1,5) CMPEX(2,6)  CMPEX(3,7)  CMPEX(8,12) CMPEX(9,13) CMPEX(10,14) CMPEX(11,15)
        CMPEX(0,2) CMPEX(1,3) CMPEX(4,6)  CMPEX(5,7)  CMPEX(8,10) CMPEX(9,11) CMPEX(12,14) CMPEX(13,15)
        CMPEX(0,1) CMPEX(2,3) CMPEX(4,5)  CMPEX(6,7)  CMPEX(8,9)  CMPEX(10,11) CMPEX(12,13) CMPEX(14,15)
#undef CMPEX
#pragma unroll
        for (int j = 0; j < CAND; ++j) { d16[j] = cd[j]; i16[j] = ci[j]; }
    }

    // ---------------- phase 2: exact fp64 rescore of 16 candidates ----------------
    // lane = channel; butterfly-sum over lanes gives every lane the exact distance
    const double qd = (double)qs[w][lane];
    double e16[CAND];
#pragma unroll
    for (int j = 0; j < CAND; ++j) {
        double dt = (double)xb[lane * NN + i16[j]] - qd;
        double part = dt * dt;
#pragma unroll
        for (int off = 1; off < 64; off <<= 1)
            part += __shfl_xor(part, off, 64);
        e16[j] = part;   // identical on all lanes
    }

    // rank-count selection of exact top-8 (smallest distance, tie -> lower index)
    float ssum = 0.f;
#pragma unroll
    for (int j = 0; j < CAND; ++j) {
        int rank = 0;
#pragma unroll
        for (int k2 = 0; k2 < CAND; ++k2)
            if (betterd(e16[k2], i16[k2], e16[j], i16[j])) ++rank;
        if (rank < KK) ssum += xb[lane * NN + i16[j]];
    }
    float mean = ssum * 0.125f;

    float* ob = out + b * (CC * 2 * NN) + lane * (2 * NN);
    ob[n]      = qs[w][lane];   // first half: copy of x
    ob[NN + n] = mean;          // second half: mean of exact 8-NN features

}

extern "C" void kernel_launch(void* const* d_in, const int* in_sizes, int n_in,
                              void* d_out, int out_size, void* d_ws, size_t ws_size,
                              hipStream_t stream) {
    (void)in_sizes; (void)n_in; (void)d_ws; (void)ws_size; (void)out_size;
    const float* x = (const float*)d_in[0];
    float* out = (float*)d_out;
    knn_upsample<<<dim3(BB * (NN / 4)), dim3(256), 0, stream>>>(x, out);
}